// Round 2
// baseline (169.217 us; speedup 1.0000x reference)
//
#include <hip/hip_runtime.h>
#include <math.h>

// CapsuleLayer dynamic routing, fused. R8: MB=2 (W traffic halved to 755 MB)
// + wave-linear W repack prepass into d_ws (perfectly coalesced 1KB/instr
// wave loads, half the L2 requests/byte) + direct-x (no LDS staging, og-quad
// broadcast coalesces from L2 free) + waves_per_eu(5,5).
// R7 diagnosis: throughput wall, not latency — occupancy +58% with 2x W
// traffic left dur flat => L2 path saturated ~16 TB/s with 64B-segment
// scattered loads (16 segments/wave-instr). R8 attacks bytes (MB=2) and
// requests/byte (repack) simultaneously. pri[] lives in AGPRs (R7 evidence:
// VGPR_Count=40 arch with 36-float pri => compiler AGPR-stashes).

#define NBATCH 256
#define NC 10
#define NR 1152
#define IC 8
#define OC 16
#define NITER 3
#define T 512
#define MB 2
#define RPT 9    // NR / 128 r-values per thread per batch
#define WP_F4 (NC * RPT * 8 * T)   // 368640 float4 = 5.9 MB packed W

// ---------------------------------------------------------------------------
// Repack W[c][r][i][o] (float4 granularity: idx ((c*NR+r)*IC+i)*4+og) into
// wave-linear Wp[((c*9+p)*8+k)*512 + t] = W[c][(t>>2)+128p][k][og=t&3].
// Main-kernel load (p,k) then reads Wp at base+ (p*8+k)*512 + t: lanes of a
// wave read 64 consecutive float4s = 1 KB contiguous.
// ---------------------------------------------------------------------------
__global__ __launch_bounds__(256)
void repack_w(const float4* __restrict__ W4, float4* __restrict__ Wp) {
    int j = blockIdx.x * 256 + threadIdx.x;      // ((c*9+p)*8+k)*512 + t
    int t  = j & 511;
    int pk = (j >> 9) % 72;
    int c  = (j >> 9) / 72;
    int p  = pk >> 3, k = pk & 7;
    int r  = (t >> 2) + (p << 7);
    int og = t & 3;
    Wp[j] = W4[(((size_t)c * NR + r) * IC + k) * 4 + og];
}

__device__ __forceinline__ float wave_sum(float v) {
#pragma unroll
    for (int m = 1; m <= 32; m <<= 1) v += __shfl_xor(v, m, 64);
    return v;
}
__device__ __forceinline__ float wave_max(float v) {
#pragma unroll
    for (int m = 1; m <= 32; m <<= 1) v = fmaxf(v, __shfl_xor(v, m, 64));
    return v;
}

template <bool PACKED>
__global__ __launch_bounds__(T)
__attribute__((amdgpu_waves_per_eu(5, 5)))   // target ~102 combined regs -> 5 waves/EU
void caps_route(
    const float* __restrict__ x,   // [B, NR, IC]
    const float4* __restrict__ Wg, // PACKED ? Wp : W (as float4)
    float* __restrict__ out)       // [B, NC, OC]
{
    __shared__ float logit0[NR];   // 4608 B
    __shared__ float logit1[NR];   // 4608 B
    __shared__ float red[2 * 128]; // per-batch: 8 waves x 16 outputs
    __shared__ float vout[2 * OC];

    const int t    = threadIdx.x;
    const int og   = t & 3;        // o-quad (o = og*4+j)
    const int rr   = t >> 2;       // 0..127
    const int lane = t & 63;
    const int wid  = t >> 6;       // 0..7

    const int c  = blockIdx.x >> 7;     // c-major: 128 consecutive blocks share W[c]
    const int bp = blockIdx.x & 127;
    const int b0 = bp * 2;              // b1 = b0+1, x rows contiguous

    // ---------------- Phase A: pri{0,1}[p] for r=rr+128p, o-quad og --------
    float4 pri0[RPT], pri1[RPT];
    const float4* __restrict__ xg0 = (const float4*)(x + (size_t)b0 * (NR * IC));
    const float4* __restrict__ xg1 = xg0 + NR * 2;

    if (PACKED) {
        const float4* __restrict__ wp = Wg + (size_t)c * (RPT * 8 * T) + t;
#pragma unroll
        for (int p = 0; p < RPT; ++p) {
            const int r = rr + (p << 7);
            float4 xa0 = xg0[2 * r], xc0 = xg0[2 * r + 1];  // og-quad broadcast
            float4 xa1 = xg1[2 * r], xc1 = xg1[2 * r + 1];
            float xv0[8] = {xa0.x, xa0.y, xa0.z, xa0.w, xc0.x, xc0.y, xc0.z, xc0.w};
            float xv1[8] = {xa1.x, xa1.y, xa1.z, xa1.w, xc1.x, xc1.y, xc1.z, xc1.w};
            float4 a0 = make_float4(0.f, 0.f, 0.f, 0.f);
            float4 a1 = make_float4(0.f, 0.f, 0.f, 0.f);
#pragma unroll
            for (int k = 0; k < 8; ++k) {
                float4 w = wp[(p * 8 + k) * T];  // 1 KB contiguous per wave
                a0.x = fmaf(xv0[k], w.x, a0.x); a1.x = fmaf(xv1[k], w.x, a1.x);
                a0.y = fmaf(xv0[k], w.y, a0.y); a1.y = fmaf(xv1[k], w.y, a1.y);
                a0.z = fmaf(xv0[k], w.z, a0.z); a1.z = fmaf(xv1[k], w.z, a1.z);
                a0.w = fmaf(xv0[k], w.w, a0.w); a1.w = fmaf(xv1[k], w.w, a1.w);
            }
            pri0[p] = a0;
            pri1[p] = a1;
        }
    } else {
        const float4* __restrict__ wb = Wg + (size_t)c * (NR * IC * 4);
#pragma unroll
        for (int p = 0; p < RPT; ++p) {
            const int r = rr + (p << 7);
            float4 xa0 = xg0[2 * r], xc0 = xg0[2 * r + 1];
            float4 xa1 = xg1[2 * r], xc1 = xg1[2 * r + 1];
            float xv0[8] = {xa0.x, xa0.y, xa0.z, xa0.w, xc0.x, xc0.y, xc0.z, xc0.w};
            float xv1[8] = {xa1.x, xa1.y, xa1.z, xa1.w, xc1.x, xc1.y, xc1.z, xc1.w};
            const float4* wp = wb + (size_t)r * 32 + og;
            float4 a0 = make_float4(0.f, 0.f, 0.f, 0.f);
            float4 a1 = make_float4(0.f, 0.f, 0.f, 0.f);
#pragma unroll
            for (int k = 0; k < 8; ++k) {
                float4 w = wp[k * 4];
                a0.x = fmaf(xv0[k], w.x, a0.x); a1.x = fmaf(xv1[k], w.x, a1.x);
                a0.y = fmaf(xv0[k], w.y, a0.y); a1.y = fmaf(xv1[k], w.y, a1.y);
                a0.z = fmaf(xv0[k], w.z, a0.z); a1.z = fmaf(xv1[k], w.z, a1.z);
                a0.w = fmaf(xv0[k], w.w, a0.w); a1.w = fmaf(xv1[k], w.w, a1.w);
            }
            pri0[p] = a0;
            pri1[p] = a1;
        }
    }

    // ---------------- Phase B: 3 routing iterations -------------------------
    for (int it = 0; it < NITER; ++it) {
        const bool uni = (it == 0);  // softmax of zeros = uniform
        float m0 = 0.f, m1 = 0.f, invd0 = 0.f, invd1 = 0.f;
        if (!uni) {
            float lm0 = -3.4e38f, lm1 = -3.4e38f;
#pragma unroll
            for (int k = 0; k < 3; ++k) {
                int r = t + (k << 9);
                if (r < NR) {
                    lm0 = fmaxf(lm0, logit0[r]);
                    lm1 = fmaxf(lm1, logit1[r]);
                }
            }
            lm0 = wave_max(lm0); lm1 = wave_max(lm1);
            if (lane == 0) { red[wid] = lm0; red[16 + wid] = lm1; }
            __syncthreads();
            m0 = red[0]; m1 = red[16];
#pragma unroll
            for (int w = 1; w < 8; ++w) {
                m0 = fmaxf(m0, red[w]); m1 = fmaxf(m1, red[16 + w]);
            }
            float ls0 = 0.f, ls1 = 0.f;
#pragma unroll
            for (int k = 0; k < 3; ++k) {
                int r = t + (k << 9);
                if (r < NR) {
                    ls0 += __expf(logit0[r] - m0);
                    ls1 += __expf(logit1[r] - m1);
                }
            }
            ls0 = wave_sum(ls0); ls1 = wave_sum(ls1);
            __syncthreads();             // m reads done before red rewrite
            if (lane == 0) { red[wid] = ls0; red[16 + wid] = ls1; }
            __syncthreads();
            float d0 = red[0], d1 = red[16];
#pragma unroll
            for (int w = 1; w < 8; ++w) { d0 += red[w]; d1 += red[16 + w]; }
            invd0 = 1.f / d0; invd1 = 1.f / d1;
        }

        // s[o] partials, both batches
        float4 s0 = make_float4(0.f, 0.f, 0.f, 0.f);
        float4 s1 = make_float4(0.f, 0.f, 0.f, 0.f);
#pragma unroll
        for (int k = 0; k < RPT; ++k) {
            float w0 = 1.0f, w1 = 1.0f;
            if (!uni) {
                const int r = rr + (k << 7);
                w0 = __expf(logit0[r] - m0);
                w1 = __expf(logit1[r] - m1);
            }
            s0.x = fmaf(w0, pri0[k].x, s0.x); s1.x = fmaf(w1, pri1[k].x, s1.x);
            s0.y = fmaf(w0, pri0[k].y, s0.y); s1.y = fmaf(w1, pri1[k].y, s1.y);
            s0.z = fmaf(w0, pri0[k].z, s0.z); s1.z = fmaf(w1, pri1[k].z, s1.z);
            s0.w = fmaf(w0, pri0[k].w, s0.w); s1.w = fmaf(w1, pri1[k].w, s1.w);
        }
        // reduce over the 16 rr slots (same og) within each wave
#pragma unroll
        for (int msk = 4; msk <= 32; msk <<= 1) {
            s0.x += __shfl_xor(s0.x, msk, 64); s1.x += __shfl_xor(s1.x, msk, 64);
            s0.y += __shfl_xor(s0.y, msk, 64); s1.y += __shfl_xor(s1.y, msk, 64);
            s0.z += __shfl_xor(s0.z, msk, 64); s1.z += __shfl_xor(s1.z, msk, 64);
            s0.w += __shfl_xor(s0.w, msk, 64); s1.w += __shfl_xor(s1.w, msk, 64);
        }
        __syncthreads();                 // stats/prev reads of red done
        if (lane < 4) {
            ((float4*)red)[wid * 4 + og]         = s0; // red[wid*16+o]
            ((float4*)(red + 128))[wid * 4 + og] = s1;
        }
        __syncthreads();

        if (t < 2 * OC) {                // t<16: batch0; 16<=t<32: batch1
            const int bsel = t >> 4, o = t & 15;
            float s = 0.f;
#pragma unroll
            for (int w = 0; w < 8; ++w) s += red[bsel * 128 + w * 16 + o];
            s *= uni ? (1.0f / 1152.0f) : (bsel ? invd1 : invd0);
            float sq = s * s;
#pragma unroll
            for (int msk = 1; msk <= 8; msk <<= 1) sq += __shfl_xor(sq, msk, 64);
            float v = s * (sqrtf(sq) / (1.0f + sq)); // squash
            if (it == NITER - 1) out[((size_t)(b0 + bsel) * NC + c) * OC + o] = v;
            else vout[t] = v;
        }
        __syncthreads();

        if (it < NITER - 1) {
            // logit[r] += sum_o pri[r][o]*v[o]
            float4 v0 = ((const float4*)vout)[og];
            float4 v1 = ((const float4*)(vout + OC))[og];
#pragma unroll
            for (int k = 0; k < RPT; ++k) {
                const int r = rr + (k << 7);
                float d0 = pri0[k].x * v0.x + pri0[k].y * v0.y +
                           pri0[k].z * v0.z + pri0[k].w * v0.w;
                float d1 = pri1[k].x * v1.x + pri1[k].y * v1.y +
                           pri1[k].z * v1.z + pri1[k].w * v1.w;
                d0 += __shfl_xor(d0, 1, 64); d1 += __shfl_xor(d1, 1, 64);
                d0 += __shfl_xor(d0, 2, 64); d1 += __shfl_xor(d1, 2, 64);
                if (og == 0) {
                    if (it == 0) { logit0[r] = d0; logit1[r] = d1; }
                    else         { logit0[r] += d0; logit1[r] += d1; }
                }
            }
            __syncthreads();
        }
    }
}

extern "C" void kernel_launch(void* const* d_in, const int* in_sizes, int n_in,
                              void* d_out, int out_size, void* d_ws, size_t ws_size,
                              hipStream_t stream) {
    const float* x = (const float*)d_in[0];
    const float* W = (const float*)d_in[1];
    float* out = (float*)d_out;
    const size_t wp_bytes = (size_t)WP_F4 * sizeof(float4);  // 5,898,240 B
    if (d_ws != nullptr && ws_size >= wp_bytes) {
        repack_w<<<dim3(WP_F4 / 256), dim3(256), 0, stream>>>(
            (const float4*)W, (float4*)d_ws);
        caps_route<true><<<dim3(NC * (NBATCH / MB)), dim3(T), 0, stream>>>(
            x, (const float4*)d_ws, out);
    } else {
        caps_route<false><<<dim3(NC * (NBATCH / MB)), dim3(T), 0, stream>>>(
            x, (const float4*)W, out);
    }
}

// Round 3
// 132.673 us; speedup vs baseline: 1.2754x; 1.2754x over previous
//
#include <hip/hip_runtime.h>
#include <math.h>

// CapsuleLayer dynamic routing, fused. R9 = R8 (MB=2, wave-linear packed W
// via d_ws repack, direct-x) with waves_per_eu(4,4) instead of (5,5).
// R8 diagnosis: (5,5) capped the unified reg budget at ~96-102 while demand
// is 72 AGPR (pri0+pri1) + 48 arch = 120 -> ~20 floats/thread SPILLED to
// scratch. Evidence: WRITE_SIZE 89.8 MB / FETCH 85.5 MB on a kernel that
// stores 160 KB. (Retro: R6's 38 MB writes were the same bug — scattered
// addressing needs 64 arch, 64+72=136 > 128.) Packed addressing (48 arch)
// + (4,4)'s 128-reg budget fits 120 with headroom -> zero spill, 2 blocks/CU,
// 72 independent contiguous 1KB wave-loads in Phase A.

#define NBATCH 256
#define NC 10
#define NR 1152
#define IC 8
#define OC 16
#define NITER 3
#define T 512
#define MB 2
#define RPT 9    // NR / 128 r-values per thread per batch
#define WP_F4 (NC * RPT * 8 * T)   // 368640 float4 = 5.9 MB packed W

// ---------------------------------------------------------------------------
// Repack W[c][r][i][o] (float4 granularity: idx ((c*NR+r)*IC+i)*4+og) into
// wave-linear Wp[((c*9+p)*8+k)*512 + t] = W[c][(t>>2)+128p][k][og=t&3].
// Main-kernel load (p,k) then reads Wp at base+ (p*8+k)*512 + t: lanes of a
// wave read 64 consecutive float4s = 1 KB contiguous.
// ---------------------------------------------------------------------------
__global__ __launch_bounds__(256)
void repack_w(const float4* __restrict__ W4, float4* __restrict__ Wp) {
    int j = blockIdx.x * 256 + threadIdx.x;      // ((c*9+p)*8+k)*512 + t
    int t  = j & 511;
    int pk = (j >> 9) % 72;
    int c  = (j >> 9) / 72;
    int p  = pk >> 3, k = pk & 7;
    int r  = (t >> 2) + (p << 7);
    int og = t & 3;
    Wp[j] = W4[(((size_t)c * NR + r) * IC + k) * 4 + og];
}

__device__ __forceinline__ float wave_sum(float v) {
#pragma unroll
    for (int m = 1; m <= 32; m <<= 1) v += __shfl_xor(v, m, 64);
    return v;
}
__device__ __forceinline__ float wave_max(float v) {
#pragma unroll
    for (int m = 1; m <= 32; m <<= 1) v = fmaxf(v, __shfl_xor(v, m, 64));
    return v;
}

template <bool PACKED>
__global__ __launch_bounds__(T)
__attribute__((amdgpu_waves_per_eu(4, 4)))   // 128-reg budget >= 120 demand: no spill
void caps_route(
    const float* __restrict__ x,   // [B, NR, IC]
    const float4* __restrict__ Wg, // PACKED ? Wp : W (as float4)
    float* __restrict__ out)       // [B, NC, OC]
{
    __shared__ float logit0[NR];   // 4608 B
    __shared__ float logit1[NR];   // 4608 B
    __shared__ float red[2 * 128]; // per-batch: 8 waves x 16 outputs
    __shared__ float vout[2 * OC];

    const int t    = threadIdx.x;
    const int og   = t & 3;        // o-quad (o = og*4+j)
    const int rr   = t >> 2;       // 0..127
    const int lane = t & 63;
    const int wid  = t >> 6;       // 0..7

    const int c  = blockIdx.x >> 7;     // c-major: 128 consecutive blocks share W[c]
    const int bp = blockIdx.x & 127;
    const int b0 = bp * 2;              // b1 = b0+1, x rows contiguous

    // ---------------- Phase A: pri{0,1}[p] for r=rr+128p, o-quad og --------
    float4 pri0[RPT], pri1[RPT];
    const float4* __restrict__ xg0 = (const float4*)(x + (size_t)b0 * (NR * IC));
    const float4* __restrict__ xg1 = xg0 + NR * 2;

    if (PACKED) {
        const float4* __restrict__ wp = Wg + (size_t)c * (RPT * 8 * T) + t;
#pragma unroll
        for (int p = 0; p < RPT; ++p) {
            const int r = rr + (p << 7);
            float4 xa0 = xg0[2 * r], xc0 = xg0[2 * r + 1];  // og-quad broadcast
            float4 xa1 = xg1[2 * r], xc1 = xg1[2 * r + 1];
            float xv0[8] = {xa0.x, xa0.y, xa0.z, xa0.w, xc0.x, xc0.y, xc0.z, xc0.w};
            float xv1[8] = {xa1.x, xa1.y, xa1.z, xa1.w, xc1.x, xc1.y, xc1.z, xc1.w};
            float4 a0 = make_float4(0.f, 0.f, 0.f, 0.f);
            float4 a1 = make_float4(0.f, 0.f, 0.f, 0.f);
#pragma unroll
            for (int k = 0; k < 8; ++k) {
                float4 w = wp[(p * 8 + k) * T];  // 1 KB contiguous per wave
                a0.x = fmaf(xv0[k], w.x, a0.x); a1.x = fmaf(xv1[k], w.x, a1.x);
                a0.y = fmaf(xv0[k], w.y, a0.y); a1.y = fmaf(xv1[k], w.y, a1.y);
                a0.z = fmaf(xv0[k], w.z, a0.z); a1.z = fmaf(xv1[k], w.z, a1.z);
                a0.w = fmaf(xv0[k], w.w, a0.w); a1.w = fmaf(xv1[k], w.w, a1.w);
            }
            pri0[p] = a0;
            pri1[p] = a1;
        }
    } else {
        const float4* __restrict__ wb = Wg + (size_t)c * (NR * IC * 4);
#pragma unroll
        for (int p = 0; p < RPT; ++p) {
            const int r = rr + (p << 7);
            float4 xa0 = xg0[2 * r], xc0 = xg0[2 * r + 1];
            float4 xa1 = xg1[2 * r], xc1 = xg1[2 * r + 1];
            float xv0[8] = {xa0.x, xa0.y, xa0.z, xa0.w, xc0.x, xc0.y, xc0.z, xc0.w};
            float xv1[8] = {xa1.x, xa1.y, xa1.z, xa1.w, xc1.x, xc1.y, xc1.z, xc1.w};
            const float4* wp = wb + (size_t)r * 32 + og;
            float4 a0 = make_float4(0.f, 0.f, 0.f, 0.f);
            float4 a1 = make_float4(0.f, 0.f, 0.f, 0.f);
#pragma unroll
            for (int k = 0; k < 8; ++k) {
                float4 w = wp[k * 4];
                a0.x = fmaf(xv0[k], w.x, a0.x); a1.x = fmaf(xv1[k], w.x, a1.x);
                a0.y = fmaf(xv0[k], w.y, a0.y); a1.y = fmaf(xv1[k], w.y, a1.y);
                a0.z = fmaf(xv0[k], w.z, a0.z); a1.z = fmaf(xv1[k], w.z, a1.z);
                a0.w = fmaf(xv0[k], w.w, a0.w); a1.w = fmaf(xv1[k], w.w, a1.w);
            }
            pri0[p] = a0;
            pri1[p] = a1;
        }
    }

    // ---------------- Phase B: 3 routing iterations -------------------------
    for (int it = 0; it < NITER; ++it) {
        const bool uni = (it == 0);  // softmax of zeros = uniform
        float m0 = 0.f, m1 = 0.f, invd0 = 0.f, invd1 = 0.f;
        if (!uni) {
            float lm0 = -3.4e38f, lm1 = -3.4e38f;
#pragma unroll
            for (int k = 0; k < 3; ++k) {
                int r = t + (k << 9);
                if (r < NR) {
                    lm0 = fmaxf(lm0, logit0[r]);
                    lm1 = fmaxf(lm1, logit1[r]);
                }
            }
            lm0 = wave_max(lm0); lm1 = wave_max(lm1);
            if (lane == 0) { red[wid] = lm0; red[16 + wid] = lm1; }
            __syncthreads();
            m0 = red[0]; m1 = red[16];
#pragma unroll
            for (int w = 1; w < 8; ++w) {
                m0 = fmaxf(m0, red[w]); m1 = fmaxf(m1, red[16 + w]);
            }
            float ls0 = 0.f, ls1 = 0.f;
#pragma unroll
            for (int k = 0; k < 3; ++k) {
                int r = t + (k << 9);
                if (r < NR) {
                    ls0 += __expf(logit0[r] - m0);
                    ls1 += __expf(logit1[r] - m1);
                }
            }
            ls0 = wave_sum(ls0); ls1 = wave_sum(ls1);
            __syncthreads();             // m reads done before red rewrite
            if (lane == 0) { red[wid] = ls0; red[16 + wid] = ls1; }
            __syncthreads();
            float d0 = red[0], d1 = red[16];
#pragma unroll
            for (int w = 1; w < 8; ++w) { d0 += red[w]; d1 += red[16 + w]; }
            invd0 = 1.f / d0; invd1 = 1.f / d1;
        }

        // s[o] partials, both batches
        float4 s0 = make_float4(0.f, 0.f, 0.f, 0.f);
        float4 s1 = make_float4(0.f, 0.f, 0.f, 0.f);
#pragma unroll
        for (int k = 0; k < RPT; ++k) {
            float w0 = 1.0f, w1 = 1.0f;
            if (!uni) {
                const int r = rr + (k << 7);
                w0 = __expf(logit0[r] - m0);
                w1 = __expf(logit1[r] - m1);
            }
            s0.x = fmaf(w0, pri0[k].x, s0.x); s1.x = fmaf(w1, pri1[k].x, s1.x);
            s0.y = fmaf(w0, pri0[k].y, s0.y); s1.y = fmaf(w1, pri1[k].y, s1.y);
            s0.z = fmaf(w0, pri0[k].z, s0.z); s1.z = fmaf(w1, pri1[k].z, s1.z);
            s0.w = fmaf(w0, pri0[k].w, s0.w); s1.w = fmaf(w1, pri1[k].w, s1.w);
        }
        // reduce over the 16 rr slots (same og) within each wave
#pragma unroll
        for (int msk = 4; msk <= 32; msk <<= 1) {
            s0.x += __shfl_xor(s0.x, msk, 64); s1.x += __shfl_xor(s1.x, msk, 64);
            s0.y += __shfl_xor(s0.y, msk, 64); s1.y += __shfl_xor(s1.y, msk, 64);
            s0.z += __shfl_xor(s0.z, msk, 64); s1.z += __shfl_xor(s1.z, msk, 64);
            s0.w += __shfl_xor(s0.w, msk, 64); s1.w += __shfl_xor(s1.w, msk, 64);
        }
        __syncthreads();                 // stats/prev reads of red done
        if (lane < 4) {
            ((float4*)red)[wid * 4 + og]         = s0; // red[wid*16+o]
            ((float4*)(red + 128))[wid * 4 + og] = s1;
        }
        __syncthreads();

        if (t < 2 * OC) {                // t<16: batch0; 16<=t<32: batch1
            const int bsel = t >> 4, o = t & 15;
            float s = 0.f;
#pragma unroll
            for (int w = 0; w < 8; ++w) s += red[bsel * 128 + w * 16 + o];
            s *= uni ? (1.0f / 1152.0f) : (bsel ? invd1 : invd0);
            float sq = s * s;
#pragma unroll
            for (int msk = 1; msk <= 8; msk <<= 1) sq += __shfl_xor(sq, msk, 64);
            float v = s * (sqrtf(sq) / (1.0f + sq)); // squash
            if (it == NITER - 1) out[((size_t)(b0 + bsel) * NC + c) * OC + o] = v;
            else vout[t] = v;
        }
        __syncthreads();

        if (it < NITER - 1) {
            // logit[r] += sum_o pri[r][o]*v[o]
            float4 v0 = ((const float4*)vout)[og];
            float4 v1 = ((const float4*)(vout + OC))[og];
#pragma unroll
            for (int k = 0; k < RPT; ++k) {
                const int r = rr + (k << 7);
                float d0 = pri0[k].x * v0.x + pri0[k].y * v0.y +
                           pri0[k].z * v0.z + pri0[k].w * v0.w;
                float d1 = pri1[k].x * v1.x + pri1[k].y * v1.y +
                           pri1[k].z * v1.z + pri1[k].w * v1.w;
                d0 += __shfl_xor(d0, 1, 64); d1 += __shfl_xor(d1, 1, 64);
                d0 += __shfl_xor(d0, 2, 64); d1 += __shfl_xor(d1, 2, 64);
                if (og == 0) {
                    if (it == 0) { logit0[r] = d0; logit1[r] = d1; }
                    else         { logit0[r] += d0; logit1[r] += d1; }
                }
            }
            __syncthreads();
        }
    }
}

extern "C" void kernel_launch(void* const* d_in, const int* in_sizes, int n_in,
                              void* d_out, int out_size, void* d_ws, size_t ws_size,
                              hipStream_t stream) {
    const float* x = (const float*)d_in[0];
    const float* W = (const float*)d_in[1];
    float* out = (float*)d_out;
    const size_t wp_bytes = (size_t)WP_F4 * sizeof(float4);  // 5,898,240 B
    if (d_ws != nullptr && ws_size >= wp_bytes) {
        repack_w<<<dim3(WP_F4 / 256), dim3(256), 0, stream>>>(
            (const float4*)W, (float4*)d_ws);
        caps_route<true><<<dim3(NC * (NBATCH / MB)), dim3(T), 0, stream>>>(
            x, (const float4*)d_ws, out);
    } else {
        caps_route<false><<<dim3(NC * (NBATCH / MB)), dim3(T), 0, stream>>>(
            x, (const float4*)W, out);
    }
}

// Round 4
// 130.557 us; speedup vs baseline: 1.2961x; 1.0162x over previous
//
#include <hip/hip_runtime.h>
#include <math.h>

// CapsuleLayer dynamic routing, fused. R10 = R7 structure (MB=1, pri=36
// floats/thread -> zero spill, direct-x) + R8/R9's wave-linear packed W.
// R9 diagnosis: MB=2's 72 prior floats/thread + 64 arch = 136 regs can NEVER
// fit a >=4 waves/EU budget -> structural spill (WRITE_SIZE 36 MB, occ 3/EU).
// R7-vs-R9 reconciliation: R7's 16.3 TB/s L2 "wall" with 64B segments is
// exactly half the full-line rate => TRANSACTION-rate limit. Packed W gives
// full 128B lines (2x bytes/txn), so MB=1's 1.5 GB W stream costs the same
// txn count as R9's 755 MB scattered-equivalent. MB=1 buys back R7's clean
// register file: 40 arch + 36 AGPR = 76 regs, waves_per_eu(6) -> 6 waves/EU,
// no scratch at all.

#define NBATCH 256
#define NC 10
#define NR 1152
#define IC 8
#define OC 16
#define NITER 3
#define T 512
#define RPT 9    // NR / 128 r-values per thread
#define WP_F4 (NC * RPT * 8 * T)   // 368640 float4 = 5.9 MB packed W

// ---------------------------------------------------------------------------
// Repack W[c][r][i][o] (float4 granularity: idx ((c*NR+r)*IC+i)*4+og) into
// wave-linear Wp[((c*9+p)*8+k)*512 + t] = W[c][(t>>2)+128p][k][og=t&3].
// Main-kernel load (p,k) reads Wp at base + (p*8+k)*512 + t: a wave reads
// 64 consecutive float4s = 1 KB contiguous = 8 full 128B lines.
// ---------------------------------------------------------------------------
__global__ __launch_bounds__(256)
void repack_w(const float4* __restrict__ W4, float4* __restrict__ Wp) {
    int j = blockIdx.x * 256 + threadIdx.x;      // ((c*9+p)*8+k)*512 + t
    int t  = j & 511;
    int pk = (j >> 9) % 72;
    int c  = (j >> 9) / 72;
    int p  = pk >> 3, k = pk & 7;
    int r  = (t >> 2) + (p << 7);
    int og = t & 3;
    Wp[j] = W4[(((size_t)c * NR + r) * IC + k) * 4 + og];
}

__device__ __forceinline__ float wave_sum(float v) {
#pragma unroll
    for (int m = 1; m <= 32; m <<= 1) v += __shfl_xor(v, m, 64);
    return v;
}
__device__ __forceinline__ float wave_max(float v) {
#pragma unroll
    for (int m = 1; m <= 32; m <<= 1) v = fmaxf(v, __shfl_xor(v, m, 64));
    return v;
}

template <bool PACKED>
__global__ __launch_bounds__(T)
__attribute__((amdgpu_waves_per_eu(6)))   // budget ~85 >= 76 demand: no spill, 6/EU
void caps_route(
    const float* __restrict__ x,   // [B, NR, IC]
    const float4* __restrict__ Wg, // PACKED ? Wp : W (as float4)
    float* __restrict__ out)       // [B, NC, OC]
{
    __shared__ float logit[NR];    // 4608 B
    __shared__ float red[128];     // 8 waves x 16 outputs
    __shared__ float vout[OC];

    const int t    = threadIdx.x;
    const int og   = t & 3;        // o-quad (o = og*4+j)
    const int rr   = t >> 2;       // 0..127
    const int lane = t & 63;
    const int wid  = t >> 6;       // 0..7

    const int c = blockIdx.x >> 8;     // c-major: 256 consecutive blocks share W[c]
    const int b = blockIdx.x & 255;

    // ---------------- Phase A: pri[p] for r=rr+128p, o-quad og --------------
    float4 pri[RPT];
    const float4* __restrict__ xg = (const float4*)(x + (size_t)b * (NR * IC));

    if (PACKED) {
        const float4* __restrict__ wp = Wg + (size_t)c * (RPT * 8 * T) + t;
#pragma unroll
        for (int p = 0; p < RPT; ++p) {
            const int r = rr + (p << 7);
            float4 xa = xg[2 * r], xc = xg[2 * r + 1];   // og-quad broadcast
            float xv[8] = {xa.x, xa.y, xa.z, xa.w, xc.x, xc.y, xc.z, xc.w};
            float4 a = make_float4(0.f, 0.f, 0.f, 0.f);
#pragma unroll
            for (int k = 0; k < 8; ++k) {
                float4 w = wp[(p * 8 + k) * T];          // 1 KB contiguous/wave
                a.x = fmaf(xv[k], w.x, a.x);
                a.y = fmaf(xv[k], w.y, a.y);
                a.z = fmaf(xv[k], w.z, a.z);
                a.w = fmaf(xv[k], w.w, a.w);
            }
            pri[p] = a;
        }
    } else {
        const float4* __restrict__ wb = Wg + (size_t)c * (NR * IC * 4);
#pragma unroll
        for (int p = 0; p < RPT; ++p) {
            const int r = rr + (p << 7);
            float4 xa = xg[2 * r], xc = xg[2 * r + 1];
            float xv[8] = {xa.x, xa.y, xa.z, xa.w, xc.x, xc.y, xc.z, xc.w};
            const float4* wp = wb + (size_t)r * 32 + og;
            float4 a = make_float4(0.f, 0.f, 0.f, 0.f);
#pragma unroll
            for (int k = 0; k < 8; ++k) {
                float4 w = wp[k * 4];
                a.x = fmaf(xv[k], w.x, a.x);
                a.y = fmaf(xv[k], w.y, a.y);
                a.z = fmaf(xv[k], w.z, a.z);
                a.w = fmaf(xv[k], w.w, a.w);
            }
            pri[p] = a;
        }
    }

    // ---------------- Phase B: 3 routing iterations -------------------------
    for (int it = 0; it < NITER; ++it) {
        const bool uni = (it == 0);  // softmax of zeros = uniform
        float m = 0.f, invd = 0.f;
        if (!uni) {
            float lm = -3.4e38f;
#pragma unroll
            for (int k = 0; k < 3; ++k) {
                int r = t + (k << 9);
                if (r < NR) lm = fmaxf(lm, logit[r]);
            }
            lm = wave_max(lm);
            if (lane == 0) red[wid] = lm;
            __syncthreads();
            m = red[0];
#pragma unroll
            for (int w = 1; w < 8; ++w) m = fmaxf(m, red[w]);
            float ls = 0.f;
#pragma unroll
            for (int k = 0; k < 3; ++k) {
                int r = t + (k << 9);
                if (r < NR) ls += __expf(logit[r] - m);
            }
            ls = wave_sum(ls);
            __syncthreads();             // m reads of red done before rewrite
            if (lane == 0) red[wid] = ls;
            __syncthreads();
            float d = red[0];
#pragma unroll
            for (int w = 1; w < 8; ++w) d += red[w];
            invd = 1.f / d;
        }

        // s[o] partials
        float4 s = make_float4(0.f, 0.f, 0.f, 0.f);
#pragma unroll
        for (int k = 0; k < RPT; ++k) {
            float w = 1.0f;
            if (!uni) w = __expf(logit[rr + (k << 7)] - m);
            s.x = fmaf(w, pri[k].x, s.x);
            s.y = fmaf(w, pri[k].y, s.y);
            s.z = fmaf(w, pri[k].z, s.z);
            s.w = fmaf(w, pri[k].w, s.w);
        }
        // reduce over the 16 rr slots (same og) within each wave
#pragma unroll
        for (int msk = 4; msk <= 32; msk <<= 1) {
            s.x += __shfl_xor(s.x, msk, 64);
            s.y += __shfl_xor(s.y, msk, 64);
            s.z += __shfl_xor(s.z, msk, 64);
            s.w += __shfl_xor(s.w, msk, 64);
        }
        __syncthreads();                 // stats reads of red done
        if (lane < 4) ((float4*)red)[wid * 4 + og] = s;  // red[wid*16+o]
        __syncthreads();

        if (t < OC) {
            float sv = 0.f;
#pragma unroll
            for (int w = 0; w < 8; ++w) sv += red[w * 16 + t];
            sv *= uni ? (1.0f / 1152.0f) : invd;
            float sq = sv * sv;
#pragma unroll
            for (int msk = 1; msk <= 8; msk <<= 1) sq += __shfl_xor(sq, msk, 64);
            float v = sv * (sqrtf(sq) / (1.0f + sq)); // squash
            if (it == NITER - 1) out[((size_t)b * NC + c) * OC + t] = v;
            else vout[t] = v;
        }
        __syncthreads();

        if (it < NITER - 1) {
            // logit[r] += sum_o pri[r][o]*v[o]
            float4 v4 = ((const float4*)vout)[og];
#pragma unroll
            for (int k = 0; k < RPT; ++k) {
                const int r = rr + (k << 7);
                float d = pri[k].x * v4.x + pri[k].y * v4.y +
                          pri[k].z * v4.z + pri[k].w * v4.w;
                d += __shfl_xor(d, 1, 64);   // sum the 4 og partials
                d += __shfl_xor(d, 2, 64);
                if (og == 0) {
                    if (it == 0) logit[r] = d;
                    else         logit[r] += d;
                }
            }
            __syncthreads();
        }
    }
}

extern "C" void kernel_launch(void* const* d_in, const int* in_sizes, int n_in,
                              void* d_out, int out_size, void* d_ws, size_t ws_size,
                              hipStream_t stream) {
    const float* x = (const float*)d_in[0];
    const float* W = (const float*)d_in[1];
    float* out = (float*)d_out;
    const size_t wp_bytes = (size_t)WP_F4 * sizeof(float4);  // 5,898,240 B
    if (d_ws != nullptr && ws_size >= wp_bytes) {
        repack_w<<<dim3(WP_F4 / 256), dim3(256), 0, stream>>>(
            (const float4*)W, (float4*)d_ws);
        caps_route<true><<<dim3(NC * NBATCH), dim3(T), 0, stream>>>(
            x, (const float4*)d_ws, out);
    } else {
        caps_route<false><<<dim3(NC * NBATCH), dim3(T), 0, stream>>>(
            x, (const float4*)W, out);
    }
}